// Round 7
// baseline (462.037 us; speedup 1.0000x reference)
//
#include <hip/hip_runtime.h>
#include <hip/hip_bf16.h>
#include <math.h>

#define DEG   6
#define MM    49      // (DEG+1)^2
#define REPC  10
#define JD    14      // 2B
#define JK    196     // JD*JD
#define PROJD 64

// factorials 0..12 (exact in double)
__device__ __constant__ double FACT[13] = {
    1.,1.,2.,6.,24.,120.,720.,5040.,40320.,362880.,3628800.,39916800.,479001600.};

// packed offsets of d^l matrices: cumulative sum of (2l+1)^2
__device__ __constant__ int DOFF[8] = {0,1,10,35,84,165,286,455};

__device__ inline double ipow_d(double b, int e) {
    double r = 1.0;
    for (int i = 0; i < e; ++i) r *= b;
    return r;
}

__device__ inline int l_of_lm(int lm) {
    int l = 0;
    while ((l + 1) * (l + 1) <= lm) ++l;
    return l;
}

// ---------------------------------------------------------------------------
// Fully fused, zero-workspace decoder. One block per sample.
// fp32 inputs (per reference setup_inputs), fp32 output (reference output
// dtype is float32 -> harness expects float*).
// ---------------------------------------------------------------------------
__global__ __launch_bounds__(256) void fused_decode(
    const float* __restrict__ angles,
    const float* __restrict__ spectrum,
    const float* __restrict__ wt,
    const float* __restrict__ bt,
    float* __restrict__ out) {
    const int n = blockIdx.x;
    const int tid = threadIdx.x;
    const float PI = 3.14159265358979323846f;

    __shared__ float dmat[455];
    __shared__ float SreL[MM][REPC];
    __shared__ float SimL[MM][REPC];
    __shared__ float sigL[REPC * JK];       // 1960 floats: signal (r, j, k)
    __shared__ float projL[REPC][34][35];   // padded rows
    __shared__ float wL[REPC * 16];
    // static LDS total = 61,820 B  (< 64 KB static limit)

    const float alpha = angles[n * 3 + 0];
    const float beta  = angles[n * 3 + 1];
    const float gamma = angles[n * 3 + 2];

    for (int i = tid; i < REPC * 16; i += 256)
        wL[i] = wt[i];

    // ---- phase 1: Wigner small-d entries (455 total, packed per l) ----
    {
        double cb = cos((double)beta * 0.5);
        double sb = sin((double)beta * 0.5);
        for (int idx = tid; idx < 455; idx += 256) {
            int l = 0;
            while (idx >= DOFF[l + 1]) ++l;
            int tl = 2 * l + 1;
            int loc = idx - DOFF[l];
            int mp = loc / tl - l;
            int m  = loc % tl - l;
            double pref = sqrt(FACT[l + mp] * FACT[l - mp] * FACT[l + m] * FACT[l - m]);
            int k0 = max(0, m - mp), k1 = min(l + m, l - mp);
            double dsum = 0.0;
            for (int k = k0; k <= k1; ++k) {
                double c = pref / (FACT[l + m - k] * FACT[k] * FACT[l - mp - k] * FACT[mp - m + k]);
                if ((mp - m + k) & 1) c = -c;
                dsum += c * ipow_d(cb, 2 * l + m - mp - 2 * k) * ipow_d(sb, mp - m + 2 * k);
            }
            dmat[idx] = (float)dsum;
        }
    }
    __syncthreads();

    // ---- phase 2: rotated spectrum S'(lm, r) = sum_m D^l[mp,m] * S(m, r) ----
    for (int idx = tid; idx < MM * REPC; idx += 256) {
        int r = idx % REPC;
        int lm = idx / REPC;
        int l = l_of_lm(lm);
        int mp = lm - l * l - l;
        int tl = 2 * l + 1;
        float sre = 0.f, sim = 0.f;
        for (int m = -l; m <= l; ++m) {
            float d = dmat[DOFF[l] + (mp + l) * tl + (m + l)];
            float ang = (float)mp * alpha + (float)m * gamma;
            float sa, ca;
            sincosf(ang, &sa, &ca);
            float Dre = d * ca, Dim = -d * sa;
            int sidx = ((l * l + l + m) * REPC + r) * 2;
            float vr = spectrum[sidx], vi = spectrum[sidx + 1];
            sre += Dre * vr - Dim * vi;
            sim += Dre * vi + Dim * vr;
        }
        SreL[lm][r] = sre;
        SimL[lm][r] = sim;
    }
    __syncthreads();

    // ---- phase 3: S2 synthesis, Y_lm computed on the fly per (j,k) cell ----
    if (tid < JK) {
        const int j = tid / JD, k = tid % JD;
        const float bj = PI * (2.f * j + 1.f) / 28.f;   // beta_j
        const float xj = cosf(bj), sxj = sinf(bj);
        const float ak = 2.f * PI * (float)k / (float)JD;
        float accr[REPC];
        for (int r = 0; r < REPC; ++r) accr[r] = 0.f;

        float pmm = 1.f;   // P_m^m running value
        for (int m = 0; m <= DEG; ++m) {
            if (m > 0) pmm = -(2.f * m - 1.f) * sxj * pmm;
            float sm, cm;
            sincosf((float)m * ak, &sm, &cm);
            const float sgn = (m & 1) ? -1.f : 1.f;
            float p_prev2 = pmm;   // P_m^m
            float p_prev1 = 0.f;   // P_{m+1}^m once set
            for (int l = m; l <= DEG; ++l) {
                float P;
                if (l == m) {
                    P = p_prev2;
                } else if (l == m + 1) {
                    p_prev1 = (2.f * m + 1.f) * xj * p_prev2;
                    P = p_prev1;
                } else {
                    float pn = ((2.f * l - 1.f) * xj * p_prev1 - (float)(l + m - 1) * p_prev2)
                               / (float)(l - m);
                    p_prev2 = p_prev1;
                    p_prev1 = pn;
                    P = pn;
                }
                float N = sqrtf((2.f * l + 1.f) / (4.f * PI) * (float)(FACT[l - m] / FACT[l + m]));
                float pr = N * P;
                float yre_p = pr * cm, yim_p = pr * sm;
                int lmp = l * l + l + m;
                for (int r = 0; r < REPC; ++r)
                    accr[r] += SreL[lmp][r] * yre_p - SimL[lmp][r] * yim_p;
                if (m > 0) {
                    float yre_n = sgn * yre_p, yim_n = -sgn * yim_p;
                    int lmn = l * l + l - m;
                    for (int r = 0; r < REPC; ++r)
                        accr[r] += SreL[lmn][r] * yre_n - SimL[lmn][r] * yim_n;
                }
            }
        }
        for (int r = 0; r < REPC; ++r)
            sigL[r * JK + tid] = accr[r];
    }
    __syncthreads();

    const float btv = bt[0];

    // ---- phases 4+5: per output tile, grid-sample region then deconv ----
    for (int tile = 0; tile < 4; ++tile) {
        const int oy0 = (tile >> 1) * 64, ox0 = (tile & 1) * 64;
        const int iby = oy0 / 2 - 1, ibx = ox0 / 2 - 1;

        // build 34x34x10 projection region in LDS (zeros outside proj bounds)
        for (int idx = tid; idx < 34 * 34; idx += 256) {
            int ry = idx / 34, rx = idx % 34;
            int iy = iby + ry, ix = ibx + rx;
            if (iy >= 0 && iy < PROJD && ix >= 0 && ix < PROJD) {
                // on-the-fly orthographic grid + bilinear taps
                float ys = -0.8f + 1.6f * (float)iy / 63.f;
                float xs = -0.8f + 1.6f * (float)ix / 63.f;
                float rho = sqrtf(xs * xs + ys * ys);
                float theta = asinf(fminf(rho, 1.0f));
                float phi = atan2f(ys, xs);
                float gxp = (phi / PI + 1.f) * 7.f - 0.5f;
                float gyp = (2.f * theta / PI) * 7.f - 0.5f;
                float x0f = floorf(gxp), y0f = floorf(gyp);
                int x0 = (int)x0f, y0 = (int)y0f;
                float fx = gxp - x0f, fy = gyp - y0f;
                int x1 = x0 + 1, y1 = y0 + 1;
                float wx0 = 1.f - fx, wy0 = 1.f - fy;
                float w00 = wx0 * wy0, w10 = fx * wy0, w01 = wx0 * fy, w11 = fx * fy;
                w00 *= (float)((x0 >= 0) & (x0 < JD) & (y0 >= 0) & (y0 < JD));
                w10 *= (float)((x1 >= 0) & (x1 < JD) & (y0 >= 0) & (y0 < JD));
                w01 *= (float)((x0 >= 0) & (x0 < JD) & (y1 >= 0) & (y1 < JD));
                w11 *= (float)((x1 >= 0) & (x1 < JD) & (y1 >= 0) & (y1 < JD));
                int xc0 = min(max(x0, 0), JD - 1), xc1 = min(max(x1, 0), JD - 1);
                int yc0 = min(max(y0, 0), JD - 1), yc1 = min(max(y1, 0), JD - 1);
                int i00 = yc0 * JD + xc0, i10 = yc0 * JD + xc1;
                int i01 = yc1 * JD + xc0, i11 = yc1 * JD + xc1;
                for (int r = 0; r < REPC; ++r) {
                    const float* s = sigL + r * JK;
                    projL[r][ry][rx] = w00 * s[i00] + w10 * s[i10] + w01 * s[i01] + w11 * s[i11];
                }
            } else {
                for (int r = 0; r < REPC; ++r) projL[r][ry][rx] = 0.f;
            }
        }
        __syncthreads();

        // deconv: out[q] = sum_i sum_k x[i] w[k]  with  q = 2i + k - 1
        for (int idx = tid; idx < 4096; idx += 256) {
            int qly = idx >> 6, qlx = idx & 63;
            int qy = oy0 + qly, qx = ox0 + qlx;
            int iy_hi = (qy + 1) >> 1;
            int ky_hi = qy + 1 - 2 * iy_hi;       // 0 or 1
            int ky_lo = ky_hi + 2;                // 2 or 3
            int ry_hi = iy_hi - iby, ry_lo = ry_hi - 1;
            int ix_hi = (qx + 1) >> 1;
            int kx_hi = qx + 1 - 2 * ix_hi;
            int kx_lo = kx_hi + 2;
            int rx_hi = ix_hi - ibx, rx_lo = rx_hi - 1;
            float acc = btv;
            for (int r = 0; r < REPC; ++r) {
                const float* wr = wL + r * 16;
                acc += wr[ky_hi * 4 + kx_hi] * projL[r][ry_hi][rx_hi]
                     + wr[ky_hi * 4 + kx_lo] * projL[r][ry_hi][rx_lo]
                     + wr[ky_lo * 4 + kx_hi] * projL[r][ry_lo][rx_hi]
                     + wr[ky_lo * 4 + kx_lo] * projL[r][ry_lo][rx_lo];
            }
            out[n * 16384 + qy * 128 + qx] = acc;
        }
        __syncthreads();
    }
}

// ---------------------------------------------------------------------------
extern "C" void kernel_launch(void* const* d_in, const int* in_sizes, int n_in,
                              void* d_out, int out_size, void* d_ws, size_t ws_size,
                              hipStream_t stream) {
    // Match inputs by element count (robust to any input ordering):
    //   angles: 2048*3 = 6144, spectrum: 49*10*2 = 980, wt: 10*1*4*4 = 160, bt: 1
    const float* angles   = nullptr;
    const float* spectrum = nullptr;
    const float* wt       = nullptr;
    const float* bt       = nullptr;
    int n = 2048;
    for (int i = 0; i < n_in; ++i) {
        int sz = in_sizes[i];
        if (sz == 980)      spectrum = (const float*)d_in[i];
        else if (sz == 160) wt = (const float*)d_in[i];
        else if (sz == 1)   bt = (const float*)d_in[i];
        else { angles = (const float*)d_in[i]; n = sz / 3; }
    }
    float* out = (float*)d_out;
    (void)d_ws; (void)ws_size;   // zero workspace use

    fused_decode<<<n, 256, 0, stream>>>(angles, spectrum, wt, bt, out);
}